// Round 8
// baseline (44.381 us; speedup 1.0000x reference)
//
#include <hip/hip_runtime.h>

typedef unsigned short ushort_t;
typedef __bf16 bf16x8 __attribute__((ext_vector_type(8)));
typedef float f32x4 __attribute__((ext_vector_type(4)));

#define AS1 __attribute__((address_space(1)))
#define AS3 __attribute__((address_space(3)))

__device__ __forceinline__ ushort_t f2bf(float f) {
    unsigned u = __builtin_bit_cast(unsigned, f);
    u = (u + 0x7fffu + ((u >> 16) & 1u)) >> 16;
    return (ushort_t)u;
}

__device__ __forceinline__ void async16(void* lds, const void* g) {
    __builtin_amdgcn_global_load_lds((const AS1 unsigned int*)g,
                                     (AS3 unsigned int*)lds, 16, 0, 0);
}

__device__ __forceinline__ void softmax2(const float* __restrict__ sig, float& s0, float& s1) {
    float a = sig[0], b = sig[1];
    float m = fmaxf(a, b);
    float e0 = __expf(a - m), e1 = __expf(b - m);
    float inv = 1.0f / (e0 + e1);
    s0 = e0 * inv; s1 = e1 * inv;
}

// toeplitz value: W_toep[k][o]
__device__ __forceinline__ float toep_val(const float* __restrict__ Wseed, int k, int o) {
    return (k >= o) ? Wseed[(size_t)(k - o) << 10] : Wseed[o - k];
}

// ---------------- merged prep (R4-verified) ----------------
// blocks [0, 4096):    x fp32 [8192][1024] -> xb bf16, 8 elems/thread (coalesced)
// blocks [4096, 4352): 256 blocks, each a 64x64 (k,o) tile of W:
//   read Wseed rows coalesced, transpose via LDS, write Wt[o][k] bf16 coalesced.
__global__ __launch_bounds__(256) void prep_kernel(const float* __restrict__ x,
                                                   const float* __restrict__ Wseed,
                                                   const float* __restrict__ Wsig,
                                                   ushort_t* __restrict__ xb,
                                                   ushort_t* __restrict__ Wt) {
    int b = blockIdx.x;
    if (b < 4096) {
        int i = b * 256 + threadIdx.x;          // 1M threads, 8 elems each
        const float4* xp = (const float4*)x + (size_t)i * 2;
        float4 a = xp[0], c = xp[1];
        uint4 r;
        r.x = (unsigned)f2bf(a.x) | ((unsigned)f2bf(a.y) << 16);
        r.y = (unsigned)f2bf(a.z) | ((unsigned)f2bf(a.w) << 16);
        r.z = (unsigned)f2bf(c.x) | ((unsigned)f2bf(c.y) << 16);
        r.w = (unsigned)f2bf(c.z) | ((unsigned)f2bf(c.w) << 16);
        ((uint4*)xb)[i] = r;
        return;
    }
    __shared__ float T[64][65];                 // [k-within][o-within], padded
    int bb = b - 4096;                          // 0..255
    int k0 = (bb >> 4) * 64;
    int o0 = (bb & 15) * 64;
    int t = threadIdx.x;
    #pragma unroll
    for (int i = 0; i < 4; ++i) {
        int lin = t + i * 256;
        int kr = lin >> 4;
        int c4 = lin & 15;
        float4 v = *(const float4*)&Wseed[(size_t)(k0 + kr) * 1024 + o0 + c4 * 4];
        T[kr][c4 * 4 + 0] = v.x;
        T[kr][c4 * 4 + 1] = v.y;
        T[kr][c4 * 4 + 2] = v.z;
        T[kr][c4 * 4 + 3] = v.w;
    }
    __syncthreads();
    float s0, s1; softmax2(Wsig, s0, s1);
    #pragma unroll
    for (int i = 0; i < 2; ++i) {
        int lin = t + i * 256;
        int oo = lin >> 3;
        int kq = (lin & 7) * 8;
        unsigned r[4];
        #pragma unroll
        for (int q = 0; q < 4; ++q) {
            float v0 = s0 * T[kq + 2 * q + 0][oo] + s1 * toep_val(Wseed, k0 + kq + 2 * q + 0, o0 + oo);
            float v1 = s0 * T[kq + 2 * q + 1][oo] + s1 * toep_val(Wseed, k0 + kq + 2 * q + 1, o0 + oo);
            r[q] = (unsigned)f2bf(v0) | ((unsigned)f2bf(v1) << 16);
        }
        *(uint4*)&Wt[(size_t)(o0 + oo) * 1024 + k0 + kq] = make_uint4(r[0], r[1], r[2], r[3]);
    }
}

// ---------------- main GEMM: 8-phase + TRUE counted-vmcnt (T2+T3+T4+T5) ----------------
// BM=256, BN=128, BK=64, 512 threads = 8 waves (4M x 2N), grid 256 = 1 block/CU.
// TRIPLE-buffered LDS (144 KB): tile T computes from buf[T%3]; tile T+2's 6
// global_load_lds issue spread over T's phases 0-2; end-of-tile waits
// s_waitcnt vmcnt(6) -> retires ONLY tile T+1's loads (the 6 oldest), tile
// T+2's stay in flight. No vmcnt(0) drain in the main loop (m218: drain0 == 1-phase).
// Race ledger:
//  - overwrite of buf[(T+2)%3]: last read in tile T-1; all its ds_reads retired
//    (dataflow lgkm before T-1's MFMAs) before T-1's trailing barrier.
//  - read of buf[T%3] in tile T: T's 6 loads issued in tile T-2; at end of tile
//    T-1, per-wave vmcnt(6) retires them (oldest 6 of 12), then s_barrier.
//  - vmcnt integrity: bias/sig loads consumed + pinned BEFORE prologue staging;
//    no other vmem inside the loop. Tail: vmcnt(0) at T=14 (only T15's left);
//    T=15 stages nothing, waits nothing.
#define NKT 16   // 1024 / 64

__global__ __launch_bounds__(512, 2) void gemm_kernel(const ushort_t* __restrict__ Xb,
                                                      const ushort_t* __restrict__ Wt,
                                                      const float* __restrict__ bseed,
                                                      const float* __restrict__ bsig,
                                                      const float* __restrict__ asig,
                                                      float* __restrict__ out) {
    // 3 buffers x (A 16384 + B 8192) ushorts = 73728 ushorts = 144 KB
    __shared__ ushort_t lds[73728];
    ushort_t* p0 = lds;            // buf for tile T   (A at +0, B at +16384)
    ushort_t* p1 = lds + 24576;    // buf for tile T+1
    ushort_t* p2 = lds + 49152;    // buf for tile T+2 (staging target)

    const int t = threadIdx.x;        // 0..511
    const int wv = t >> 6;            // 0..7
    const int lane = t & 63;

    // XCD-aware swizzle (256 blocks, 256%8==0 -> bijective); per-XCD set:
    // Xb panel (4 row-blocks x 256 x 2KB = 2MB) + full Wt (2MB) = 4MB L2.
    const int orig = blockIdx.x;
    const int g = orig & 7;
    const int within = orig >> 3;           // 0..31
    const int rb = g * 4 + (within >> 3);   // 0..31
    const int cb = within & 7;              // 0..7
    const int brow = rb * 256;
    const int bcol = cb * 128;

    // staging map: 512 threads x 16B = 8KB = 64 rows x 64k x 2B per gload
    const int r0 = t >> 3;                  // 0..63
    const int kcs = 8 * ((t & 7) ^ (r0 & 7));   // inverse-swizzled source column
    const ushort_t* gA = Xb + (size_t)(brow + r0) * 1024 + kcs;
    const ushort_t* gB = Wt + (size_t)(bcol + r0) * 1024 + kcs;

    // fragment geometry
    const int wr = (wv >> 1) * 64;    // wave M origin (0,64,128,192)
    const int wcn = (wv & 1) * 64;    // wave N origin (0,64)
    const int fr = lane & 15;
    const int kg = (lane >> 4) * 8;
    const int frx = (fr & 7) << 3;    // ds_read XOR (ushort units)

    f32x4 acc[4][4];
    #pragma unroll
    for (int i = 0; i < 4; ++i)
        #pragma unroll
        for (int j = 0; j < 4; ++j) acc[i][j] = (f32x4){0.f, 0.f, 0.f, 0.f};
    bf16x8 bfr[4][2];

    // ---- epilogue scalars first: consume + pin so vmcnt stays clean ----
    float bs0, bs1, as0, as1;
    softmax2(bsig, bs0, bs1);
    softmax2(asig, as0, as1);
    float bias[4];
    #pragma unroll
    for (int ni = 0; ni < 4; ++ni)
        bias[ni] = bs0 * bseed[bcol + wcn + ni * 16 + fr];
    asm volatile("" :: "v"(bias[0]), "v"(bias[1]), "v"(bias[2]), "v"(bias[3]),
                       "v"(as0), "v"(as1));
    asm volatile("" ::: "memory");

#define PH(p, STAGEBLK)                                                            \
    do {                                                                           \
        const int arow_ = wr + (p) * 16 + fr;                                      \
        bf16x8 a0 = *(const bf16x8*)&p0[arow_ * 64 + ((0 + kg) ^ frx)];            \
        bf16x8 a1 = *(const bf16x8*)&p0[arow_ * 64 + ((32 + kg) ^ frx)];           \
        if ((p) == 0) {                                                            \
            _Pragma("unroll")                                                      \
            for (int ni = 0; ni < 4; ++ni) {                                       \
                int br_ = wcn + ni * 16 + fr;                                      \
                bfr[ni][0] = *(const bf16x8*)&p0[16384 + br_ * 64 + ((0 + kg) ^ frx)];  \
                bfr[ni][1] = *(const bf16x8*)&p0[16384 + br_ * 64 + ((32 + kg) ^ frx)]; \
            }                                                                      \
        }                                                                          \
        STAGEBLK                                                                   \
        asm volatile("" ::: "memory");                                             \
        __builtin_amdgcn_s_barrier();                                              \
        __builtin_amdgcn_s_setprio(1);                                             \
        _Pragma("unroll")                                                          \
        for (int ni = 0; ni < 4; ++ni) {                                           \
            acc[p][ni] = __builtin_amdgcn_mfma_f32_16x16x32_bf16(a0, bfr[ni][0],   \
                                                                 acc[p][ni], 0, 0, 0); \
            acc[p][ni] = __builtin_amdgcn_mfma_f32_16x16x32_bf16(a1, bfr[ni][1],   \
                                                                 acc[p][ni], 0, 0, 0); \
        }                                                                          \
        __builtin_amdgcn_s_setprio(0);                                             \
    } while (0)

    // prologue: tile 0 -> p0 (6 loads), tile 1 -> p1 (6 loads), wait only tile 0's
    async16(p0 + wv * 512,          gA);
    async16(p0 + 4096 + wv * 512,   gA + 65536);
    async16(p0 + 8192 + wv * 512,   gA + 131072);
    async16(p0 + 12288 + wv * 512,  gA + 196608);
    async16(p0 + 16384 + wv * 512,  gB);
    async16(p0 + 20480 + wv * 512,  gB + 65536);
    async16(p1 + wv * 512,          gA + 64);
    async16(p1 + 4096 + wv * 512,   gA + 65536 + 64);
    async16(p1 + 8192 + wv * 512,   gA + 131072 + 64);
    async16(p1 + 12288 + wv * 512,  gA + 196608 + 64);
    async16(p1 + 16384 + wv * 512,  gB + 64);
    async16(p1 + 20480 + wv * 512,  gB + 65536 + 64);
    asm volatile("s_waitcnt vmcnt(6)" ::: "memory");
    __builtin_amdgcn_s_barrier();

    for (int T = 0; T < NKT; ++T) {
        const size_t t2 = (size_t)(T + 2) * 64;
        const bool dost = (T < NKT - 2);
        PH(0, { if (dost) { async16(p2 + wv * 512,          gA + t2);
                            async16(p2 + 4096 + wv * 512,   gA + 65536 + t2); } });
        __builtin_amdgcn_s_barrier();
        PH(1, { if (dost) { async16(p2 + 8192 + wv * 512,   gA + 131072 + t2);
                            async16(p2 + 12288 + wv * 512,  gA + 196608 + t2); } });
        __builtin_amdgcn_s_barrier();
        PH(2, { if (dost) { async16(p2 + 16384 + wv * 512,  gB + t2);
                            async16(p2 + 20480 + wv * 512,  gB + 65536 + t2); } });
        __builtin_amdgcn_s_barrier();
        PH(3, {});
        if (T < NKT - 2)        { asm volatile("s_waitcnt vmcnt(6)" ::: "memory"); }
        else if (T == NKT - 2)  { asm volatile("s_waitcnt vmcnt(0)" ::: "memory"); }
        __builtin_amdgcn_s_barrier();
        ushort_t* tmp_ = p0; p0 = p1; p1 = p2; p2 = tmp_;
    }

    // epilogue: bias + activation mixture
    #pragma unroll
    for (int ni = 0; ni < 4; ++ni) {
        int col = bcol + wcn + ni * 16 + fr;
        #pragma unroll
        for (int mi = 0; mi < 4; ++mi) {
            int row = brow + wr + mi * 16 + (lane >> 4) * 4;
            #pragma unroll
            for (int r = 0; r < 4; ++r) {
                float v = acc[mi][ni][r] + bias[ni];
                out[(size_t)(row + r) * 1024 + col] = as0 * v + as1 * fmaxf(v, 0.f);
            }
        }
    }
#undef PH
}

// ---------------- fallback (only if workspace too small): naive fp32 ----------------
__global__ __launch_bounds__(256) void naive_kernel(const float* __restrict__ x,
                                                    const float* __restrict__ Wseed,
                                                    const float* __restrict__ bseed,
                                                    const float* __restrict__ Wsig,
                                                    const float* __restrict__ bsig,
                                                    const float* __restrict__ asig,
                                                    float* __restrict__ out) {
    int idx = blockIdx.x * 256 + threadIdx.x;
    int b = idx >> 10, o = idx & 1023;
    float ws0, ws1, bs0, bs1, as0, as1;
    softmax2(Wsig, ws0, ws1);
    softmax2(bsig, bs0, bs1);
    softmax2(asig, as0, as1);
    float s = 0.f;
    const float* xr = x + (size_t)b * 1024;
    for (int k = 0; k < 1024; ++k) {
        float wc = ws0 * Wseed[((size_t)k << 10) + o] + ws1 * toep_val(Wseed, k, o);
        s += xr[k] * wc;
    }
    float v = s + bs0 * bseed[o];
    out[idx] = as0 * v + as1 * fmaxf(v, 0.f);
}

extern "C" void kernel_launch(void* const* d_in, const int* in_sizes, int n_in,
                              void* d_out, int out_size, void* d_ws, size_t ws_size,
                              hipStream_t stream) {
    const float* x     = (const float*)d_in[0];
    const float* Wseed = (const float*)d_in[1];
    const float* bseed = (const float*)d_in[2];
    const float* Wsig  = (const float*)d_in[3];
    const float* bsig  = (const float*)d_in[4];
    const float* Asig  = (const float*)d_in[5];
    float* out = (float*)d_out;

    const size_t need = (2u << 20) + (16u << 20) + 1024;
    if (ws_size < need) {
        naive_kernel<<<dim3(8192 * 1024 / 256), dim3(256), 0, stream>>>(
            x, Wseed, bseed, Wsig, bsig, Asig, out);
        return;
    }

    ushort_t* Wt = (ushort_t*)d_ws;                         // 2 MB: W_core^T bf16 [1024][1024]
    ushort_t* Xb = (ushort_t*)((char*)d_ws + (2u << 20));   // 16 MB: x bf16 [8192][1024]

    prep_kernel<<<dim3(4096 + 256), dim3(256), 0, stream>>>(x, Wseed, Wsig, Xb, Wt);
    gemm_kernel<<<dim3(256), dim3(512), 0, stream>>>(Xb, Wt, bseed, bsig, Asig, out);
}

// Round 9
// 40.083 us; speedup vs baseline: 1.1072x; 1.1072x over previous
//
#include <hip/hip_runtime.h>

typedef unsigned short ushort_t;
typedef __bf16 bf16x8 __attribute__((ext_vector_type(8)));
typedef float f32x4 __attribute__((ext_vector_type(4)));

#define AS1 __attribute__((address_space(1)))
#define AS3 __attribute__((address_space(3)))

__device__ __forceinline__ ushort_t f2bf(float f) {
    unsigned u = __builtin_bit_cast(unsigned, f);
    u = (u + 0x7fffu + ((u >> 16) & 1u)) >> 16;
    return (ushort_t)u;
}

__device__ __forceinline__ void async16(void* lds, const void* g) {
    __builtin_amdgcn_global_load_lds((const AS1 unsigned int*)g,
                                     (AS3 unsigned int*)lds, 16, 0, 0);
}

__device__ __forceinline__ void softmax2(const float* __restrict__ sig, float& s0, float& s1) {
    float a = sig[0], b = sig[1];
    float m = fmaxf(a, b);
    float e0 = __expf(a - m), e1 = __expf(b - m);
    float inv = 1.0f / (e0 + e1);
    s0 = e0 * inv; s1 = e1 * inv;
}

// toeplitz value: W_toep[k][o]
__device__ __forceinline__ float toep_val(const float* __restrict__ Wseed, int k, int o) {
    return (k >= o) ? Wseed[(size_t)(k - o) << 10] : Wseed[o - k];
}

// ---------------- prep: W_core^T bf16 only (x consumed fp32 by GEMM) ----------------
// 256 blocks, each a 64x64 (k,o) tile: read Wseed rows coalesced, transpose via LDS,
// write Wt[o][k] bf16 coalesced.
__global__ __launch_bounds__(256) void prep_w_kernel(const float* __restrict__ Wseed,
                                                     const float* __restrict__ Wsig,
                                                     ushort_t* __restrict__ Wt) {
    __shared__ float T[64][65];
    int bb = blockIdx.x;                        // 0..255
    int k0 = (bb >> 4) * 64;
    int o0 = (bb & 15) * 64;
    int t = threadIdx.x;
    #pragma unroll
    for (int i = 0; i < 4; ++i) {
        int lin = t + i * 256;
        int kr = lin >> 4;
        int c4 = lin & 15;
        float4 v = *(const float4*)&Wseed[(size_t)(k0 + kr) * 1024 + o0 + c4 * 4];
        T[kr][c4 * 4 + 0] = v.x;
        T[kr][c4 * 4 + 1] = v.y;
        T[kr][c4 * 4 + 2] = v.z;
        T[kr][c4 * 4 + 3] = v.w;
    }
    __syncthreads();
    float s0, s1; softmax2(Wsig, s0, s1);
    #pragma unroll
    for (int i = 0; i < 2; ++i) {
        int lin = t + i * 256;
        int oo = lin >> 3;
        int kq = (lin & 7) * 8;
        unsigned r[4];
        #pragma unroll
        for (int q = 0; q < 4; ++q) {
            float v0 = s0 * T[kq + 2 * q + 0][oo] + s1 * toep_val(Wseed, k0 + kq + 2 * q + 0, o0 + oo);
            float v1 = s0 * T[kq + 2 * q + 1][oo] + s1 * toep_val(Wseed, k0 + kq + 2 * q + 1, o0 + oo);
            r[q] = (unsigned)f2bf(v0) | ((unsigned)f2bf(v1) << 16);
        }
        *(uint4*)&Wt[(size_t)(o0 + oo) * 1024 + k0 + kq] = make_uint4(r[0], r[1], r[2], r[3]);
    }
}

// ---------------- main GEMM: fused x->bf16 staging (T14 on 3-deep pipeline) --------
// BM=256, BN=128, BK=64, 512 threads = 8 waves (4M x 2N), grid 256 = 1 block/CU.
// Triple-buffered LDS (144 KB). A is staged from fp32 x: global_load_dwordx4 into
// regs at tile T's ph0/ph1 (for tile T+1, ~3 phases of lead), cvt+ds_write at ph3.
// B stays async16 from Wt with 2-tile lead. Counted waits by issue-order ledger:
//   steady in-flight at T ph3: B(T+1)x2 (oldest), A(T+1)x8, B(T+2)x2 (newest)
//   -> s_waitcnt vmcnt(2) retires B(T+1)+A(T+1); never drains B(T+2).
// Tail: T=14 -> vmcnt(0); T=15 stages/waits nothing.
// Race ledger:
//  - WRITEA -> p1 (tile T+1's buffer): no reader during tile T; lgkmcnt(0)+barrier
//    before T+1's ph0 reads.
//  - async16 B(T+2) -> p2: last read as tile T-1's cur buffer, done pre-barrier.
//  - vmcnt integrity: bias/sig scalars consumed+pinned before prologue staging.
#define NKT 16   // 1024 / 64

__global__ __launch_bounds__(512, 1) void gemm_kernel(const float* __restrict__ Xf,
                                                      const ushort_t* __restrict__ Wt,
                                                      const float* __restrict__ bseed,
                                                      const float* __restrict__ bsig,
                                                      const float* __restrict__ asig,
                                                      float* __restrict__ out) {
    // 3 buffers x (A 16384 + B 8192) ushorts = 144 KB
    __shared__ ushort_t lds[73728];
    ushort_t* p0 = lds;            // tile T   (A at +0, B at +16384)
    ushort_t* p1 = lds + 24576;    // tile T+1
    ushort_t* p2 = lds + 49152;    // tile T+2

    const int t = threadIdx.x;        // 0..511
    const int wv = t >> 6;            // 0..7
    const int lane = t & 63;

    // XCD-aware swizzle (256 blocks, bijective)
    const int orig = blockIdx.x;
    const int g = orig & 7;
    const int within = orig >> 3;           // 0..31
    const int rb = g * 4 + (within >> 3);   // 0..31
    const int cb = within & 7;              // 0..7
    const int brow = rb * 256;
    const int bcol = cb * 128;

    // staging map: thread t covers 8 elems of row r0 (+64*grp for A), col pre-XOR'd
    const int r0 = t >> 3;                      // 0..63
    const int kcs = 8 * ((t & 7) ^ (r0 & 7));   // element offset (inverse swizzle)
    const float*    gXf = Xf + (size_t)(brow + r0) * 1024 + kcs;
    const ushort_t* gB  = Wt + (size_t)(bcol + r0) * 1024 + kcs;

    // fragment geometry
    const int wr = (wv >> 1) * 64;
    const int wcn = (wv & 1) * 64;
    const int fr = lane & 15;
    const int kg = (lane >> 4) * 8;
    const int frx = (fr & 7) << 3;

    f32x4 acc[4][4];
    #pragma unroll
    for (int i = 0; i < 4; ++i)
        #pragma unroll
        for (int j = 0; j < 4; ++j) acc[i][j] = (f32x4){0.f, 0.f, 0.f, 0.f};
    bf16x8 bfr[4][2];
    f32x4 ar[8];   // A staging regs: 4 row-groups x 8 floats (statically indexed)

    // ---- epilogue scalars first: consume + pin so vmcnt stays clean ----
    float bs0, bs1, as0, as1;
    softmax2(bsig, bs0, bs1);
    softmax2(asig, as0, as1);
    float bias[4];
    #pragma unroll
    for (int ni = 0; ni < 4; ++ni)
        bias[ni] = bs0 * bseed[bcol + wcn + ni * 16 + fr];
    asm volatile("" :: "v"(bias[0]), "v"(bias[1]), "v"(bias[2]), "v"(bias[3]),
                       "v"(as0), "v"(as1));
    asm volatile("" ::: "memory");

#define LOADA2(g0, koff)                                                           \
    do {                                                                           \
        ar[2*(g0)]   = *(const f32x4*)(gXf + (g0) * 65536 + (koff));               \
        ar[2*(g0)+1] = *(const f32x4*)(gXf + (g0) * 65536 + (koff) + 4);           \
    } while (0)

#define WRITEA(dstA)                                                               \
    do {                                                                           \
        _Pragma("unroll")                                                          \
        for (int g_ = 0; g_ < 4; ++g_) {                                           \
            bf16x8 v_;                                                             \
            _Pragma("unroll")                                                      \
            for (int j_ = 0; j_ < 4; ++j_) {                                       \
                v_[j_]     = (__bf16)ar[2 * g_][j_];                               \
                v_[4 + j_] = (__bf16)ar[2 * g_ + 1][j_];                           \
            }                                                                      \
            *(bf16x8*)&(dstA)[g_ * 4096 + t * 8] = v_;                             \
        }                                                                          \
    } while (0)

#define PH(p, STAGEBLK)                                                            \
    do {                                                                           \
        const int arow_ = wr + (p) * 16 + fr;                                      \
        bf16x8 a0 = *(const bf16x8*)&p0[arow_ * 64 + ((0 + kg) ^ frx)];            \
        bf16x8 a1 = *(const bf16x8*)&p0[arow_ * 64 + ((32 + kg) ^ frx)];           \
        if ((p) == 0) {                                                            \
            _Pragma("unroll")                                                      \
            for (int ni = 0; ni < 4; ++ni) {                                       \
                int br_ = wcn + ni * 16 + fr;                                      \
                bfr[ni][0] = *(const bf16x8*)&p0[16384 + br_ * 64 + ((0 + kg) ^ frx)];  \
                bfr[ni][1] = *(const bf16x8*)&p0[16384 + br_ * 64 + ((32 + kg) ^ frx)]; \
            }                                                                      \
        }                                                                          \
        STAGEBLK                                                                   \
        asm volatile("" ::: "memory");                                             \
        __builtin_amdgcn_s_barrier();                                              \
        __builtin_amdgcn_s_setprio(1);                                             \
        _Pragma("unroll")                                                          \
        for (int ni = 0; ni < 4; ++ni) {                                           \
            acc[p][ni] = __builtin_amdgcn_mfma_f32_16x16x32_bf16(a0, bfr[ni][0],   \
                                                                 acc[p][ni], 0, 0, 0); \
            acc[p][ni] = __builtin_amdgcn_mfma_f32_16x16x32_bf16(a1, bfr[ni][1],   \
                                                                 acc[p][ni], 0, 0, 0); \
        }                                                                          \
        __builtin_amdgcn_s_setprio(0);                                             \
    } while (0)

    // ---- prologue: A(0) via regs, B(0)->p0, B(1)->p1 ----
    LOADA2(0, 0); LOADA2(1, 0); LOADA2(2, 0); LOADA2(3, 0);     // 8 vm
    async16(p0 + 16384 + wv * 512, gB);                          // B(0) 2 vm
    async16(p0 + 20480 + wv * 512, gB + 65536);
    async16(p1 + 16384 + wv * 512, gB + 64);                     // B(1) 2 vm
    async16(p1 + 20480 + wv * 512, gB + 65536 + 64);
    asm volatile("s_waitcnt vmcnt(4)" ::: "memory");             // retire A(0)
    __builtin_amdgcn_sched_barrier(0);
    WRITEA(p0);
    asm volatile("s_waitcnt vmcnt(2)" ::: "memory");             // retire B(0)
    asm volatile("s_waitcnt lgkmcnt(0)" ::: "memory");
    __builtin_amdgcn_s_barrier();

    for (int T = 0; T < NKT; ++T) {
        const size_t ka = (size_t)(T + 1) * 64;   // A lead: 1 tile (3 phases)
        const size_t kb = (size_t)(T + 2) * 64;   // B lead: 2 tiles
        PH(0, { if (T < NKT - 1) { LOADA2(0, ka); LOADA2(1, ka); } });
        __builtin_amdgcn_s_barrier();
        PH(1, { if (T < NKT - 1) { LOADA2(2, ka); LOADA2(3, ka); } });
        __builtin_amdgcn_s_barrier();
        PH(2, { if (T < NKT - 2) { async16(p2 + 16384 + wv * 512, gB + kb);
                                   async16(p2 + 20480 + wv * 512, gB + 65536 + kb); } });
        __builtin_amdgcn_s_barrier();
        PH(3, {});
        if (T < NKT - 2)       { asm volatile("s_waitcnt vmcnt(2)" ::: "memory"); }
        else if (T == NKT - 2) { asm volatile("s_waitcnt vmcnt(0)" ::: "memory"); }
        __builtin_amdgcn_sched_barrier(0);
        if (T < NKT - 1) WRITEA(p1);
        asm volatile("s_waitcnt lgkmcnt(0)" ::: "memory");
        __builtin_amdgcn_s_barrier();
        ushort_t* tmp_ = p0; p0 = p1; p1 = p2; p2 = tmp_;
    }

    // epilogue: bias + activation mixture
    #pragma unroll
    for (int ni = 0; ni < 4; ++ni) {
        int col = bcol + wcn + ni * 16 + fr;
        #pragma unroll
        for (int mi = 0; mi < 4; ++mi) {
            int row = brow + wr + mi * 16 + (lane >> 4) * 4;
            #pragma unroll
            for (int r = 0; r < 4; ++r) {
                float v = acc[mi][ni][r] + bias[ni];
                out[(size_t)(row + r) * 1024 + col] = as0 * v + as1 * fmaxf(v, 0.f);
            }
        }
    }
#undef PH
#undef LOADA2
#undef WRITEA
}

// ---------------- fallback (only if workspace too small): naive fp32 ----------------
__global__ __launch_bounds__(256) void naive_kernel(const float* __restrict__ x,
                                                    const float* __restrict__ Wseed,
                                                    const float* __restrict__ bseed,
                                                    const float* __restrict__ Wsig,
                                                    const float* __restrict__ bsig,
                                                    const float* __restrict__ asig,
                                                    float* __restrict__ out) {
    int idx = blockIdx.x * 256 + threadIdx.x;
    int b = idx >> 10, o = idx & 1023;
    float ws0, ws1, bs0, bs1, as0, as1;
    softmax2(Wsig, ws0, ws1);
    softmax2(bsig, bs0, bs1);
    softmax2(asig, as0, as1);
    float s = 0.f;
    const float* xr = x + (size_t)b * 1024;
    for (int k = 0; k < 1024; ++k) {
        float wc = ws0 * Wseed[((size_t)k << 10) + o] + ws1 * toep_val(Wseed, k, o);
        s += xr[k] * wc;
    }
    float v = s + bs0 * bseed[o];
    out[idx] = as0 * v + as1 * fmaxf(v, 0.f);
}

extern "C" void kernel_launch(void* const* d_in, const int* in_sizes, int n_in,
                              void* d_out, int out_size, void* d_ws, size_t ws_size,
                              hipStream_t stream) {
    const float* x     = (const float*)d_in[0];
    const float* Wseed = (const float*)d_in[1];
    const float* bseed = (const float*)d_in[2];
    const float* Wsig  = (const float*)d_in[3];
    const float* bsig  = (const float*)d_in[4];
    const float* Asig  = (const float*)d_in[5];
    float* out = (float*)d_out;

    const size_t need = (2u << 20) + 1024;
    if (ws_size < need) {
        naive_kernel<<<dim3(8192 * 1024 / 256), dim3(256), 0, stream>>>(
            x, Wseed, bseed, Wsig, bsig, Asig, out);
        return;
    }

    ushort_t* Wt = (ushort_t*)d_ws;   // 2 MB: W_core^T bf16 [1024][1024]

    prep_w_kernel<<<dim3(256), dim3(256), 0, stream>>>(Wseed, Wsig, Wt);
    gemm_kernel<<<dim3(256), dim3(512), 0, stream>>>(x, Wt, bseed, bsig, Asig, out);
}